// Round 4
// baseline (240.176 us; speedup 1.0000x reference)
//
#include <hip/hip_runtime.h>

#define N_IMG    1024
#define N_VIEWS  90
#define CENTER   512
#define NTHREADS 256
#define NWAVES   4
#define BUFW     1536      // words per wave buffer; worst job = 36 rows * 41 pitch = 1476
#define NJOBS    8         // y-jobs (16 rows) per wave segment (128 rows)

typedef float v2f __attribute__((ext_vector_type(2)));

// x_in =  ca*X + sa*Y + cx,  cx = CENTER*(1 - ca - sa)
// y_in = -sa*X + ca*Y + cy,  cy = CENTER*(1 - ca + sa)
// Fixed fmaf chain: corner extremes == sample extremes (monotone per variable).
__device__ __forceinline__ void map_coords(float ca, float sa, float cx, float cy,
                                           float Xf, float Yf,
                                           float& x_in, float& y_in) {
    const float fx0 = fmaf(ca, Xf, cx);
    const float fy0 = fmaf(-sa, Xf, cy);
    x_in = fmaf(sa, Yf, fx0);
    y_in = fmaf(ca, Yf, fy0);
}

// global->LDS DMA: global address is PER-LANE; LDS dest is wave-uniform base
// (HW writes base + lane*width). Exec-masked: inactive lanes write nothing.
__device__ __forceinline__ void gload_lds4(const float* g, float* l) {
    __builtin_amdgcn_global_load_lds((const __attribute__((address_space(1))) void*)g,
                                     (__attribute__((address_space(3))) void*)l, 4, 0, 0);
}
__device__ __forceinline__ void gload_lds16(const float* g, float* l) {
    __builtin_amdgcn_global_load_lds((const __attribute__((address_space(1))) void*)g,
                                     (__attribute__((address_space(3))) void*)l, 16, 0, 0);
}

// Bilinear sampler — identical numerics to the verified engine (YPT=8, pairs
// on float2 ext-vectors, incremental coords with drift <= 4e-4 px). A +-1
// floor overshoot from drift reads a ~0-weight word that stays inside the
// wave's padded buffer (stale value, bounded) or LDS-OOB (returns 0).
template<int P>
__device__ __forceinline__ float sample8(const float* __restrict__ tile,
                                         float sa, float ca,
                                         float x_in, float y_in, float basef) {
    const float Sf = (float)P;
    v2f x2 = {x_in, x_in + sa};
    v2f y2 = {y_in, y_in + ca};
    const v2f dx2 = {2.0f * sa, 2.0f * sa};
    const v2f dy2 = {2.0f * ca, 2.0f * ca};
    const v2f S2  = {Sf, Sf};
    const v2f b2  = {basef, basef};
    v2f acc2 = {0.0f, 0.0f};
    #pragma unroll
    for (int p = 0; p < 4; ++p) {
        v2f x0f = {floorf(x2.x), floorf(x2.y)};
        v2f y0f = {floorf(y2.x), floorf(y2.y)};
        const v2f wx = x2 - x0f;
        const v2f wy = y2 - y0f;
        const v2f lif = y0f * S2 + x0f + b2;     // exact < 2^23
        const int li0 = (int)lif.x;
        const int li1 = (int)lif.y;
        const v2f t00 = {tile[li0],          tile[li1]};
        const v2f t01 = {tile[li0 + 1],      tile[li1 + 1]};
        const v2f t10 = {tile[li0 + P],      tile[li1 + P]};
        const v2f t11 = {tile[li0 + P + 1],  tile[li1 + P + 1]};
        const v2f top = (t01 - t00) * wx + t00;
        const v2f bot = (t11 - t10) * wx + t10;
        acc2 += (bot - top) * wy + top;
        x2 += dx2; y2 += dy2;
    }
    return acc2.x + acc2.y;
}

// One WAVE owns (angle, 32-col x-strip, 128-row y-segment): 8 sequential
// 32x16 jobs, each: stage own bbox -> per-wave vmcnt(0) -> sample. No
// __syncthreads anywhere. P = LDS pitch (odd -> conflict-free), WS = staged
// cols (mult of 4 for 16B DMA), P = WS+1.
template<int P, int WS>
__device__ float run_seg(const float* __restrict__ img, float* __restrict__ buf,
                         float sa, float ca, float cx, float cy,
                         int X0i, int Ys, int lane) {
    const float Xf  = (float)(X0i + (lane & 31));
    const float fx0 = fmaf(ca, Xf, cx);
    const float fy0 = fmaf(-sa, Xf, cy);
    const int  yoff = (lane >> 5) << 3;          // 0 or 8
    const float Xc0 = (float)X0i, Xc1 = (float)(X0i + 31);
    float acc = 0.0f;

    for (int jj = 0; jj < NJOBS; ++jj) {
        const float Y0f = (float)(Ys + jj * 16);
        const float Y1f = Y0f + 15.0f;
        // exact per-job bbox corners (no incremental drift on the bbox)
        float x00, y00, x01, y01, x10, y10, x11, y11;
        map_coords(ca, sa, cx, cy, Xc0, Y0f, x00, y00);
        map_coords(ca, sa, cx, cy, Xc1, Y0f, x01, y01);
        map_coords(ca, sa, cx, cy, Xc0, Y1f, x10, y10);
        map_coords(ca, sa, cx, cy, Xc1, Y1f, x11, y11);
        const float xmin = fminf(fminf(x00, x01), fminf(x10, x11));
        const float xmax = fmaxf(fmaxf(x00, x01), fmaxf(x10, x11));
        const float ymin = fminf(fminf(y00, y01), fminf(y10, y11));
        const float ymax = fmaxf(fmaxf(y00, y01), fmaxf(y10, y11));
        const int ix0 = (int)floorf(xmin);
        const int ix1 = (int)floorf(xmax) + 1;   // rightmost tap; ix1-ix0 <= 35
        const int iy0 = (int)floorf(ymin);
        const int iy1 = (int)floorf(ymax) + 1;   // bottom tap;   iy1-iy0 <= 36

        if (ix1 < 0 || ix0 > N_IMG - 1 || iy1 < 0 || iy0 > N_IMG - 1)
            continue;                            // wave-uniform: fully outside

        int win = ix0 & ~3;                      // 4-aligned window start
        const bool interior = (ix0 >= 0) && (ix1 <= N_IMG - 1) &&
                              (iy0 >= 0) && (iy1 <= N_IMG - 1);
        const int R = iy1 - iy0 + 1;             // staged rows <= 37

        if (interior) {
            win = min(win, N_IMG - WS);          // keep all 16B chunks in-image
            // per-row 16B DMA: lanes 0..WS/4-1 cover WS cols; LDS rows at odd
            // pitch P (col P-1 never written/sampled)
            int gb = iy0 * N_IMG + win;
            float* lb = buf;
            for (int r = 0; r < R; ++r) {
                if (lane < WS / 4)
                    gload_lds16(img + gb + 4 * lane, lb);
                gb += N_IMG;
                lb += P;
            }
        } else {
            // border: masked per-word DMA; off-image words -> 0 (ds_write)
            const int D = R * P;
            for (int d0 = lane; d0 < D; d0 += 64) {
                const int r  = (int)((unsigned)d0 / (unsigned)P);  // const div
                const int c  = d0 - r * P;
                const int gy = iy0 + r;
                const int gx = win + c;
                float* lb = buf + (d0 - lane);   // wave-uniform chunk base
                if ((unsigned)gy < (unsigned)N_IMG && (unsigned)gx < (unsigned)N_IMG)
                    gload_lds4(img + (size_t)gy * N_IMG + gx, lb);
                else
                    buf[d0] = 0.0f;
            }
        }
        // per-wave drain: DMA data visible to this wave's ds_reads. No barrier.
        asm volatile("s_waitcnt vmcnt(0)" ::: "memory");

        const float Ybf  = Y0f + (float)yoff;
        const float x_in = fmaf(sa, Ybf, fx0);
        const float y_in = fmaf(ca, Ybf, fy0);
        const float basef = -(float)(iy0 * P + win);
        acc += sample8<P>(buf, sa, ca, x_in, y_in, basef);
    }
    return acc;
}

__global__ __launch_bounds__(NTHREADS, 6) void radon_waves(const float* __restrict__ img,
                                                           const float* __restrict__ theta,
                                                           float* __restrict__ out) {
    __shared__ float lds[NWAVES][BUFW];   // 24 KB -> 6 blocks/CU = 24 waves

    const int tid  = threadIdx.x;
    const int lane = tid & 63;
    const int wv   = tid >> 6;
    const int wid  = blockIdx.x * NWAVES + wv;    // [0, 23040)
    const int a    = wid >> 8;                    // 256 waves per angle
    const int rem  = wid & 255;
    const int X0   = (rem & 31) << 5;             // 32 x-strips of 32
    const int Ys   = (rem >> 5) << 7;             // 8 y-segments of 128

    const float ang = theta[a] * 0.017453292519943295f;
    float sa, ca;
    __sincosf(ang, &sa, &ca);
    const float cx = (float)CENTER * (1.0f - ca - sa);
    const float cy = (float)CENTER * (1.0f - ca + sa);

    // per-angle stride class: Wneed = ceil(31|ca|+15|sa|) + 5 in [20,40];
    // WS = round-up to mult of 4, P = WS+1 (odd -> conflict-free LDS pitch)
    const float aca = fabsf(ca), asa = fabsf(sa);
    const int Wneed = (int)ceilf(fmaf(31.0f, aca, 15.0f * asa)) + 5;
    const int cls   = ((Wneed + 3) >> 2) - 5;     // 0..5
    float* buf = &lds[wv][0];

    float acc;
    switch (cls) {
        case 0:  acc = run_seg<21, 20>(img, buf, sa, ca, cx, cy, X0, Ys, lane); break;
        case 1:  acc = run_seg<25, 24>(img, buf, sa, ca, cx, cy, X0, Ys, lane); break;
        case 2:  acc = run_seg<29, 28>(img, buf, sa, ca, cx, cy, X0, Ys, lane); break;
        case 3:  acc = run_seg<33, 32>(img, buf, sa, ca, cx, cy, X0, Ys, lane); break;
        case 4:  acc = run_seg<37, 36>(img, buf, sa, ca, cx, cy, X0, Ys, lane); break;
        default: acc = run_seg<41, 40>(img, buf, sa, ca, cx, cy, X0, Ys, lane); break;
    }

    // lanes L and L+32 hold the two y-halves of column X0+(L&31)
    const float tot = acc + __shfl_xor(acc, 32);
    if (lane < 32)
        atomicAdd(&out[(size_t)(X0 + lane) * N_VIEWS + a], tot);
}

extern "C" void kernel_launch(void* const* d_in, const int* in_sizes, int n_in,
                              void* d_out, int out_size, void* d_ws, size_t ws_size,
                              hipStream_t stream) {
    const float* img   = (const float*)d_in[0];   // [1024, 1024] f32
    const float* theta = (const float*)d_in[1];   // [90] f32 degrees
    float* out = (float*)d_out;                   // [1024, 90] f32
    (void)d_ws; (void)ws_size;

    (void)hipMemsetAsync(d_out, 0, (size_t)out_size * sizeof(float), stream);
    // 23040 wave-jobs: 90 angles x 32 x-strips x 8 y-segments; 4 waves/block
    radon_waves<<<dim3(23040 / NWAVES), NTHREADS, 0, stream>>>(img, theta, out);
}

// Round 5
// 144.616 us; speedup vs baseline: 1.6608x; 1.6608x over previous
//
#include <hip/hip_runtime.h>

#define N_IMG    1024
#define N_VIEWS  90
#define CENTER   512
#define NTHREADS 256
#define NWAVES   4
#define NJOBS    8         // 8 jobs of 64x32 per block = 256-row y-quarter
#define BUFW     5120      // 20 KB -> 8 blocks/CU = 32 waves (full wave cap)
// worst-case staged region (driftless exact bbox): rows*P <= (R+3)(W+4),
// W=63|c|+31|s|, R=63|s|+31|c| -> max ~4896 @45deg < 5120. No drift pads
// needed because sample coords are EXACT pk_fma of integer Y (no increments).

typedef float v2f __attribute__((ext_vector_type(2)));

// x_in =  ca*X + sa*Y + cx,  cx = CENTER*(1 - ca - sa)
// y_in = -sa*X + ca*Y + cy,  cy = CENTER*(1 - ca + sa)
// Fixed fmaf chain; samples use the SAME chain (outer fma in Y), so corner
// extremes bound every sample tap exactly (fma monotone per argument).
__device__ __forceinline__ void map_coords(float ca, float sa, float cx, float cy,
                                           float Xf, float Yf,
                                           float& x_in, float& y_in) {
    const float fx0 = fmaf(ca, Xf, cx);
    const float fy0 = fmaf(-sa, Xf, cy);
    x_in = fmaf(sa, Yf, fx0);
    y_in = fmaf(ca, Yf, fy0);
}

// global->LDS DMA: global address PER-LANE, LDS dest = wave-uniform base +
// lane*4. Exec-masked: inactive lanes write nothing (validated R2/R4).
__device__ __forceinline__ void gload_lds4(const float* g, float* l) {
    __builtin_amdgcn_global_load_lds((const __attribute__((address_space(1))) void*)g,
                                     (__attribute__((address_space(3))) void*)l, 4, 0, 0);
}

// One block = (angle, 64-col x-tile, 256-row y-quarter): 8 sequential 64x32
// jobs. stage (all-lane 4B DMA, exact bbox, odd pitch) -> sync -> sample ->
// sync. 8 independent blocks/CU hide each other's drains.
__global__ __launch_bounds__(NTHREADS, 8) void radon_q(const float* __restrict__ img,
                                                       const float* __restrict__ theta,
                                                       float* __restrict__ out) {
    __shared__ float buf[BUFW];          // 20 KB exactly

    const int tx = blockIdx.x;
    const int q  = blockIdx.y;
    const int a  = blockIdx.z;
    const int X0 = tx * 64;
    const int Yq = q * (NJOBS * 32);     // 0,256,512,768
    const int tid  = threadIdx.x;
    const int lane = tid & 63;
    const int wv   = tid >> 6;           // 0..3

    // ---- block-uniform per-angle params ----
    const float ang = theta[a] * 0.017453292519943295f;
    float sa, ca;
    __sincosf(ang, &sa, &ca);
    const float cx = (float)CENTER * (1.0f - ca - sa);
    const float cy = (float)CENTER * (1.0f - ca + sa);

    // ---- per-lane sample-line constants (lane = output column) ----
    const float Xf  = (float)(X0 + lane);
    const float fx0 = fmaf(ca, Xf, cx);
    const float fy0 = fmaf(-sa, Xf, cy);
    const v2f sa2 = {sa, sa};
    const v2f ca2 = {ca, ca};
    const v2f fx2 = {fx0, fx0};
    const v2f fy2 = {fy0, fy0};
    float acc = 0.0f;

    for (int j = 0; j < NJOBS; ++j) {
        // ---- exact job bbox (uniform across threads) ----
        const float Y0f = (float)(Yq + j * 32);
        const float Y1f = Y0f + 31.0f;
        float x00, y00, x01, y01, x10, y10, x11, y11;
        map_coords(ca, sa, cx, cy, (float)X0,        Y0f, x00, y00);
        map_coords(ca, sa, cx, cy, (float)(X0 + 63), Y0f, x01, y01);
        map_coords(ca, sa, cx, cy, (float)X0,        Y1f, x10, y10);
        map_coords(ca, sa, cx, cy, (float)(X0 + 63), Y1f, x11, y11);
        const float xmin = fminf(fminf(x00, x01), fminf(x10, x11));
        const float xmax = fmaxf(fmaxf(x00, x01), fmaxf(x10, x11));
        const float ymin = fminf(fminf(y00, y01), fminf(y10, y11));
        const float ymax = fmaxf(fmaxf(y00, y01), fmaxf(y10, y11));
        const int ix0 = (int)floorf(xmin);
        const int ix1 = (int)floorf(xmax) + 1;   // rightmost tap (incl. +1)
        const int iy0 = (int)floorf(ymin);
        const int iy1 = (int)floorf(ymax) + 1;   // bottom tap (incl. +1)

        if (ix1 < 0 || ix0 > N_IMG - 1 || iy1 < 0 || iy0 > N_IMG - 1)
            continue;                            // uniform: job fully outside

        const bool interior = (ix0 >= 0) && (ix1 <= N_IMG - 1) &&
                              (iy0 >= 0) && (iy1 <= N_IMG - 1);
        const int win = ix0;                     // exact window start (no align)
        const int WS  = ix1 - ix0 + 1;           // staged cols, 34..73
        const int P   = WS | 1;                  // odd LDS pitch
        const int R   = iy1 - iy0 + 1;           // staged rows, 34..71

        // ---- staging: rows r = wv, wv+4, ... (all 64 lanes per row) ----
        if (interior) {
            const float* g = img + (size_t)(iy0 + wv) * N_IMG + win;
            float* l = buf + wv * P;
            if (WS <= 64) {
                for (int r = wv; r < R; r += NWAVES) {
                    if (lane < WS) gload_lds4(g + lane, l);
                    g += NWAVES * N_IMG;
                    l += NWAVES * P;
                }
            } else {
                for (int r = wv; r < R; r += NWAVES) {
                    gload_lds4(g + lane, l);
                    if (lane < WS - 64) gload_lds4(g + 64 + lane, l + 64);
                    g += NWAVES * N_IMG;
                    l += NWAVES * P;
                }
            }
        } else {
            // border: per-lane masked DMA; off-image words -> ds_write 0
            for (int r = wv; r < R; r += NWAVES) {
                const int gy = iy0 + r;
                const bool rok = ((unsigned)gy < (unsigned)N_IMG);
                const float* gp = img + (size_t)gy * N_IMG;
                float* l = buf + r * P;
                const int gx = win + lane;
                if (lane < WS) {
                    if (rok && (unsigned)gx < (unsigned)N_IMG) gload_lds4(gp + gx, l);
                    else l[lane] = 0.0f;
                }
                if (WS > 64) {
                    const int gx2 = gx + 64;
                    if (lane < WS - 64) {
                        if (rok && (unsigned)gx2 < (unsigned)N_IMG) gload_lds4(gp + gx2, l + 64);
                        else l[64 + lane] = 0.0f;
                    }
                }
            }
        }
        __syncthreads();     // drains this block's DMA; staging visible

        // ---- sample 8 dst rows (wave wv -> rows j*32 + wv*8 ..+8) ----
        // exact coords: x = fma(sa, Y, fx0) per sample (no incremental drift)
        const float Yb = Y0f + (float)(wv * 8);
        const float Pf = (float)P;
        const v2f P2 = {Pf, Pf};
        const float basef = -(float)(iy0 * P + win);
        const v2f b2 = {basef, basef};
        v2f Y2 = {Yb, Yb + 1.0f};
        const v2f two2 = {2.0f, 2.0f};
        v2f acc2 = {0.0f, 0.0f};
        #pragma unroll
        for (int p = 0; p < 4; ++p) {
            const v2f x2 = sa2 * Y2 + fx2;       // v_pk_fma (exact chain)
            const v2f y2 = ca2 * Y2 + fy2;
            v2f x0f = {floorf(x2.x), floorf(x2.y)};
            v2f y0f = {floorf(y2.x), floorf(y2.y)};
            const v2f wx = x2 - x0f;
            const v2f wy = y2 - y0f;
            const v2f lif = y0f * P2 + x0f + b2; // exact (< 2^23)
            const int li0 = (int)lif.x;
            const int li1 = (int)lif.y;
            const int li0p = li0 + P;
            const int li1p = li1 + P;
            const v2f t00 = {buf[li0],      buf[li1]};        // ds_read2
            const v2f t01 = {buf[li0 + 1],  buf[li1 + 1]};
            const v2f t10 = {buf[li0p],     buf[li1p]};       // ds_read2
            const v2f t11 = {buf[li0p + 1], buf[li1p + 1]};
            const v2f top = (t01 - t00) * wx + t00;
            const v2f bot = (t11 - t10) * wx + t10;
            acc2 += (bot - top) * wy + top;
            Y2 += two2;
        }
        acc += acc2.x + acc2.y;

        __syncthreads();     // all waves done reading before next staging
    }

    // ---- block reduce (overlay buf) + atomic merge of 4 y-quarters ----
    buf[tid] = acc;
    __syncthreads();
    if (tid < 64) {
        const float s = buf[tid] + buf[tid + 64] + buf[tid + 128] + buf[tid + 192];
        atomicAdd(&out[(size_t)(X0 + tid) * N_VIEWS + a], s);
    }
}

extern "C" void kernel_launch(void* const* d_in, const int* in_sizes, int n_in,
                              void* d_out, int out_size, void* d_ws, size_t ws_size,
                              hipStream_t stream) {
    const float* img   = (const float*)d_in[0];   // [1024, 1024] f32
    const float* theta = (const float*)d_in[1];   // [90] f32 degrees
    float* out = (float*)d_out;                   // [1024, 90] f32
    (void)d_ws; (void)ws_size;

    (void)hipMemsetAsync(d_out, 0, (size_t)out_size * sizeof(float), stream);
    radon_q<<<dim3(16, 4, N_VIEWS), NTHREADS, 0, stream>>>(img, theta, out);
}